// Round 1
// baseline (949.081 us; speedup 1.0000x reference)
//
#include <hip/hip_runtime.h>

// MoE FFN: D=1024, H=4096, E=8, top-2, T=4096 tokens, fp32 in/out, bf16 MFMA compute.

#define T_TOKENS 4096
#define DM 1024
#define HID 4096
#define NE 8

typedef __attribute__((ext_vector_type(8))) short short8;
typedef __attribute__((ext_vector_type(4))) float f32x4;
typedef unsigned short u16;

__device__ __forceinline__ u16 f2b(float f) {
    unsigned u = __builtin_bit_cast(unsigned, f);
    u += 0x7FFFu + ((u >> 16) & 1u);   // round-to-nearest-even
    return (u16)(u >> 16);
}

__device__ __forceinline__ uint4 load8(const u16* p) {
    return *(const uint4*)p;           // 8 bf16 = 16 B
}
__device__ __forceinline__ uint4 load8(const float* p) {
    const float4* q = (const float4*)p;
    float4 a = q[0], b = q[1];
    uint4 r;
    r.x = (unsigned)f2b(a.x) | ((unsigned)f2b(a.y) << 16);
    r.y = (unsigned)f2b(a.z) | ((unsigned)f2b(a.w) << 16);
    r.z = (unsigned)f2b(b.x) | ((unsigned)f2b(b.y) << 16);
    r.w = (unsigned)f2b(b.z) | ((unsigned)f2b(b.w) << 16);
    return r;
}

__global__ __launch_bounds__(256) void cvt_bf16_kernel(const float* __restrict__ src,
                                                       u16* __restrict__ dst, long n) {
    long i = ((long)blockIdx.x * 256 + threadIdx.x) * 8;
    if (i >= n) return;
    *(uint4*)(dst + i) = load8(src + i);
}

// fp32 gating: one wave per token. bf16 gating would flip near-tie expert picks.
__global__ __launch_bounds__(256) void gate_kernel(const float* __restrict__ x,
                                                   const float* __restrict__ gw,
                                                   int* __restrict__ cnt,
                                                   int2* __restrict__ topidx,
                                                   float2* __restrict__ topg) {
    int t = blockIdx.x * 4 + (threadIdx.x >> 6);
    int lane = threadIdx.x & 63;
    const float* xr = x + (long)t * DM;
    float s[NE];
#pragma unroll
    for (int e = 0; e < NE; e++) s[e] = 0.f;
    for (int i = lane; i < DM; i += 64) {
        float xv = xr[i];
#pragma unroll
        for (int e = 0; e < NE; e++) s[e] += xv * gw[e * DM + i];
    }
#pragma unroll
    for (int e = 0; e < NE; e++)
        for (int o = 32; o > 0; o >>= 1) s[e] += __shfl_down(s[e], o);
    if (lane == 0) {
        int i0 = 0; float l0 = s[0];
#pragma unroll
        for (int e = 1; e < NE; e++) if (s[e] > l0) { l0 = s[e]; i0 = e; }
        int i1 = -1; float l1 = -1e30f;
#pragma unroll
        for (int e = 0; e < NE; e++) if (e != i0 && s[e] > l1) { l1 = s[e]; i1 = e; }
        float e1 = __expf(l1 - l0);
        float inv = 1.f / (1.f + e1);
        topidx[t] = make_int2(i0, i1);
        topg[t]   = make_float2(inv, e1 * inv);
        atomicAdd(&cnt[i0], 1);
        atomicAdd(&cnt[i1], 1);
    }
}

__global__ void prefix_kernel(const int* __restrict__ cnt, int* __restrict__ offs) {
    if (threadIdx.x == 0) {
        int a = 0;
        for (int e = 0; e < NE; e++) { offs[e] = a; a += cnt[e]; }
    }
}

__global__ __launch_bounds__(256) void scatter_kernel(const int2* __restrict__ topidx,
                                                      const float2* __restrict__ topg,
                                                      const int* __restrict__ offs,
                                                      int* __restrict__ fill,
                                                      int* __restrict__ tok,
                                                      float* __restrict__ gate) {
    int t = blockIdx.x * 256 + threadIdx.x;
    if (t >= T_TOKENS) return;
    int2 ix = topidx[t]; float2 g = topg[t];
    int p = atomicAdd(&fill[ix.x], 1);
    int sl = offs[ix.x] + p;
    tok[sl] = t; gate[sl] = g.x;
    p = atomicAdd(&fill[ix.y], 1);
    sl = offs[ix.y] + p;
    tok[sl] = t; gate[sl] = g.y;
}

// C[M,N] = A[M,K] * B[N,K]^T  (both K-contiguous; torch Linear weight layout).
// MODE 0: shared L1  -> silu -> bf16 store          (rows direct)
// MODE 1: shared L2  -> f32 store to out            (rows direct)
// MODE 2: expert L1  -> gathered token rows, silu -> bf16 store at slot rows
// MODE 3: expert L2  -> slot rows direct, gate-scaled atomicAdd into out
template<typename TB, int MODE>
__global__ __launch_bounds__(256)
void gemm_bt(const u16* __restrict__ A, int lda,
             const TB* __restrict__ Bbase, int ldb, long strideB, int K,
             int Mstatic,
             const int* __restrict__ cnt, const int* __restrict__ offs,
             const int* __restrict__ tok_of_slot, const float* __restrict__ gate_of_slot,
             u16* __restrict__ Cb, int ldcb,
             float* __restrict__ Cf, int ldcf) {
    int M = Mstatic, base = 0;
    const TB* B = Bbase;
    if constexpr (MODE >= 2) {
        int e = blockIdx.z;
        base = offs[e];
        M = cnt[e];
        B = Bbase + (long)e * strideB;
    }
    const int m0 = blockIdx.y * 128;
    if (m0 >= M) return;
    const int n0 = blockIdx.x * 128;

    __shared__ u16 As[128][40];   // +8 pad: breaks pow-2 bank stride
    __shared__ u16 Bs[128][40];

    const int tid  = threadIdx.x;
    const int lane = tid & 63;
    const int wid  = tid >> 6;
    const int wm   = (wid >> 1) * 64;
    const int wn   = (wid & 1) * 64;
    const int lr   = lane & 15;
    const int lk   = (lane >> 4) * 8;

    // Per-thread staging chunks: c = tid, tid+256; row=c>>2, kcol=(c&3)*8
    int arow_r[2], akc[2];
    long aoff[2], boff[2];
#pragma unroll
    for (int i = 0; i < 2; i++) {
        int c = tid + i * 256;
        int r = c >> 2, kc = (c & 3) * 8;
        arow_r[i] = r; akc[i] = kc;
        int rr = m0 + r;
        if (rr >= M) rr = M - 1;       // clamp tail rows (stores are guarded)
        long grow;
        if constexpr (MODE == 2)      grow = tok_of_slot[base + rr];
        else if constexpr (MODE == 3) grow = (long)(base + rr);
        else                          grow = rr;
        aoff[i] = grow * (long)lda + kc;
        boff[i] = (long)(n0 + r) * ldb + kc;
    }

    f32x4 acc[4][4];
#pragma unroll
    for (int mi = 0; mi < 4; mi++)
#pragma unroll
        for (int ni = 0; ni < 4; ni++)
            acc[mi][ni] = (f32x4){0.f, 0.f, 0.f, 0.f};

    for (int k0 = 0; k0 < K; k0 += 32) {
#pragma unroll
        for (int i = 0; i < 2; i++) {
            *(uint4*)&As[arow_r[i]][akc[i]] = load8(A + aoff[i] + k0);
            *(uint4*)&Bs[arow_r[i]][akc[i]] = load8(B + boff[i] + k0);
        }
        __syncthreads();
        short8 af[4], bfr[4];
#pragma unroll
        for (int mi = 0; mi < 4; mi++) af[mi]  = *(const short8*)&As[wm + mi * 16 + lr][lk];
#pragma unroll
        for (int ni = 0; ni < 4; ni++) bfr[ni] = *(const short8*)&Bs[wn + ni * 16 + lr][lk];
#pragma unroll
        for (int mi = 0; mi < 4; mi++)
#pragma unroll
            for (int ni = 0; ni < 4; ni++)
                acc[mi][ni] = __builtin_amdgcn_mfma_f32_16x16x32_bf16(af[mi], bfr[ni],
                                                                      acc[mi][ni], 0, 0, 0);
        __syncthreads();
    }

    // Epilogue. C/D layout: col = lane&15, row = (lane>>4)*4 + reg  [m89-verified]
    const int r4 = (lane >> 4) * 4;
    const int cl = lane & 15;
#pragma unroll
    for (int mi = 0; mi < 4; mi++) {
#pragma unroll
        for (int rr = 0; rr < 4; rr++) {
            int row = m0 + wm + mi * 16 + r4 + rr;
            if constexpr (MODE >= 2) { if (row >= M) continue; }
            int t = 0; float g = 0.f;
            if constexpr (MODE == 3) {
                t = tok_of_slot[base + row];
                g = gate_of_slot[base + row];
            }
#pragma unroll
            for (int ni = 0; ni < 4; ni++) {
                int col = n0 + wn + ni * 16 + cl;
                float v = acc[mi][ni][rr];
                if constexpr (MODE == 0) {
                    float s = v / (1.f + __expf(-v));
                    Cb[(long)row * ldcb + col] = f2b(s);
                } else if constexpr (MODE == 1) {
                    Cf[(long)row * ldcf + col] = v;
                } else if constexpr (MODE == 2) {
                    float s = v / (1.f + __expf(-v));
                    Cb[(long)(base + row) * ldcb + col] = f2b(s);
                } else {
                    atomicAdd(&Cf[(long)t * ldcf + col], g * v);
                }
            }
        }
    }
}

extern "C" void kernel_launch(void* const* d_in, const int* in_sizes, int n_in,
                              void* d_out, int out_size, void* d_ws, size_t ws_size,
                              hipStream_t stream) {
    const float* x   = (const float*)d_in[0];
    const float* sw1 = (const float*)d_in[1];
    const float* sw2 = (const float*)d_in[2];
    const float* ew1 = (const float*)d_in[3];
    const float* ew2 = (const float*)d_in[4];
    const float* gw  = (const float*)d_in[5];
    float* out = (float*)d_out;

    char* ws = (char*)d_ws;
    size_t off = 0;
    auto alloc = [&](size_t bytes) -> char* {
        off = (off + 255) & ~(size_t)255;
        char* p = ws + off;
        off += bytes;
        return p;
    };

    int*    meta   = (int*)alloc(256);          // cnt[8] | fill[8] | offs[8]
    int*    cnt    = meta;
    int*    fill   = meta + 8;
    int*    offs   = meta + 16;
    int2*   topidx = (int2*)alloc((size_t)T_TOKENS * 8);
    float2* topg   = (float2*)alloc((size_t)T_TOKENS * 8);
    int*    tok    = (int*)alloc((size_t)2 * T_TOKENS * 4);
    float*  gate   = (float*)alloc((size_t)2 * T_TOKENS * 4);
    u16* xb   = (u16*)alloc((size_t)T_TOKENS * DM * 2);
    u16* sw1b = (u16*)alloc((size_t)HID * DM * 2);
    u16* sw2b = (u16*)alloc((size_t)DM * HID * 2);
    u16* hidS = (u16*)alloc((size_t)T_TOKENS * HID * 2);
    u16* hidE = (u16*)alloc((size_t)2 * T_TOKENS * HID * 2);

    const size_t ew_bytes = (size_t)NE * HID * DM * 2;   // 64 MB each
    bool cvt_ew = (ws_size >= off + 2 * ew_bytes + 1024);
    u16 *ew1b = nullptr, *ew2b = nullptr;
    if (cvt_ew) {
        ew1b = (u16*)alloc(ew_bytes);
        ew2b = (u16*)alloc(ew_bytes);
    }

    hipMemsetAsync(meta, 0, 64, stream);  // zero cnt+fill

    // fp32 -> bf16 conversions
    cvt_bf16_kernel<<<(T_TOKENS * DM) / 2048, 256, 0, stream>>>(x, xb, (long)T_TOKENS * DM);
    cvt_bf16_kernel<<<(HID * DM) / 2048, 256, 0, stream>>>(sw1, sw1b, (long)HID * DM);
    cvt_bf16_kernel<<<(DM * HID) / 2048, 256, 0, stream>>>(sw2, sw2b, (long)DM * HID);
    if (cvt_ew) {
        cvt_bf16_kernel<<<(NE * HID * DM) / 2048, 256, 0, stream>>>(ew1, ew1b, (long)NE * HID * DM);
        cvt_bf16_kernel<<<(NE * DM * HID) / 2048, 256, 0, stream>>>(ew2, ew2b, (long)NE * DM * HID);
    }

    gate_kernel<<<T_TOKENS / 4, 256, 0, stream>>>(x, gw, cnt, topidx, topg);
    prefix_kernel<<<1, 64, 0, stream>>>(cnt, offs);
    scatter_kernel<<<T_TOKENS / 256, 256, 0, stream>>>(topidx, topg, offs, fill, tok, gate);

    dim3 blk(256);
    // shared L1: [T,1024] x [4096,1024]^T -> silu -> hidS (bf16)
    gemm_bt<u16, 0><<<dim3(HID / 128, T_TOKENS / 128), blk, 0, stream>>>(
        xb, DM, sw1b, DM, 0, DM, T_TOKENS,
        nullptr, nullptr, nullptr, nullptr, hidS, HID, nullptr, 0);
    // expert L1: gathered rows, per-expert weights
    if (cvt_ew)
        gemm_bt<u16, 2><<<dim3(HID / 128, T_TOKENS / 128, NE), blk, 0, stream>>>(
            xb, DM, ew1b, DM, (long)HID * DM, DM, 0,
            cnt, offs, tok, gate, hidE, HID, nullptr, 0);
    else
        gemm_bt<float, 2><<<dim3(HID / 128, T_TOKENS / 128, NE), blk, 0, stream>>>(
            xb, DM, ew1, DM, (long)HID * DM, DM, 0,
            cnt, offs, tok, gate, hidE, HID, nullptr, 0);
    // shared L2: [T,4096] x [1024,4096]^T -> out (plain f32 store, full coverage)
    gemm_bt<u16, 1><<<dim3(DM / 128, T_TOKENS / 128), blk, 0, stream>>>(
        hidS, HID, sw2b, HID, 0, HID, T_TOKENS,
        nullptr, nullptr, nullptr, nullptr, nullptr, 0, out, DM);
    // expert L2: gate-scaled atomic add into out (stream-ordered after shared L2)
    if (cvt_ew)
        gemm_bt<u16, 3><<<dim3(DM / 128, T_TOKENS / 128, NE), blk, 0, stream>>>(
            hidE, HID, ew2b, HID, (long)DM * HID, HID, 0,
            cnt, offs, tok, gate, nullptr, 0, out, DM);
    else
        gemm_bt<float, 3><<<dim3(DM / 128, T_TOKENS / 128, NE), blk, 0, stream>>>(
            hidE, HID, ew2, HID, (long)DM * HID, HID, 0,
            cnt, offs, tok, gate, nullptr, 0, out, DM);
}

// Round 2
// 940.117 us; speedup vs baseline: 1.0095x; 1.0095x over previous
//
#include <hip/hip_runtime.h>

// MoE FFN: D=1024, H=4096, E=8, top-2, T=4096 tokens, fp32 in/out, bf16 MFMA compute.
// R2: m97-style async staging (global_load_lds width=16) + global-side XOR swizzle
// to keep unpadded LDS conflict-light; fused single cvt kernel.

#define T_TOKENS 4096
#define DM 1024
#define HID 4096
#define NE 8

typedef __attribute__((ext_vector_type(8))) short short8;
typedef __attribute__((ext_vector_type(4))) float f32x4;
typedef unsigned short u16;

__device__ __forceinline__ u16 f2b(float f) {
    unsigned u = __builtin_bit_cast(unsigned, f);
    u += 0x7FFFu + ((u >> 16) & 1u);   // round-to-nearest-even
    return (u16)(u >> 16);
}

__device__ __forceinline__ uint4 load8(const u16* p) {
    return *(const uint4*)p;           // 8 bf16 = 16 B
}
__device__ __forceinline__ uint4 load8(const float* p) {
    const float4* q = (const float4*)p;
    float4 a = q[0], b = q[1];
    uint4 r;
    r.x = (unsigned)f2b(a.x) | ((unsigned)f2b(a.y) << 16);
    r.y = (unsigned)f2b(a.z) | ((unsigned)f2b(a.w) << 16);
    r.z = (unsigned)f2b(b.x) | ((unsigned)f2b(b.y) << 16);
    r.w = (unsigned)f2b(b.z) | ((unsigned)f2b(b.w) << 16);
    return r;
}

// async 16B global -> LDS (wave-uniform lds base + lane*16)
__device__ __forceinline__ void gld16(const u16* g, u16* lds) {
    __builtin_amdgcn_global_load_lds(
        (const __attribute__((address_space(1))) void*)g,
        (__attribute__((address_space(3))) void*)lds, 16, 0, 0);
}

// ---- fused fp32 -> bf16 conversion of all tensors --------------------------
constexpr long CN0 = (long)T_TOKENS * DM;        // x
constexpr long CN1 = CN0 + (long)HID * DM;       // sw1
constexpr long CN2 = CN1 + (long)DM * HID;       // sw2
constexpr long CN3 = CN2 + (long)NE * HID * DM;  // ew1
constexpr long CN4 = CN3 + (long)NE * DM * HID;  // ew2

template<bool FULL>
__global__ __launch_bounds__(256) void cvt_all_kernel(
    const float* __restrict__ x,  const float* __restrict__ sw1,
    const float* __restrict__ sw2, const float* __restrict__ ew1,
    const float* __restrict__ ew2,
    u16* __restrict__ xb, u16* __restrict__ sw1b, u16* __restrict__ sw2b,
    u16* __restrict__ ew1b, u16* __restrict__ ew2b) {
    long i = ((long)blockIdx.x * 256 + threadIdx.x) * 8;
    const float* s; u16* d; long base;
    if (i < CN0)      { s = x;   d = xb;   base = 0;   }
    else if (i < CN1) { s = sw1; d = sw1b; base = CN0; }
    else if (i < CN2) { s = sw2; d = sw2b; base = CN1; }
    else if (FULL && i < CN3) { s = ew1; d = ew1b; base = CN2; }
    else if (FULL && i < CN4) { s = ew2; d = ew2b; base = CN3; }
    else return;
    long j = i - base;
    *(uint4*)(d + j) = load8(s + j);
}

// ---- gating (fp32: bf16 logits would flip near-tie expert picks) -----------
__global__ __launch_bounds__(256) void gate_kernel(const float* __restrict__ x,
                                                   const float* __restrict__ gw,
                                                   int* __restrict__ cnt,
                                                   int2* __restrict__ topidx,
                                                   float2* __restrict__ topg) {
    int t = blockIdx.x * 4 + (threadIdx.x >> 6);
    int lane = threadIdx.x & 63;
    const float* xr = x + (long)t * DM;
    float s[NE];
#pragma unroll
    for (int e = 0; e < NE; e++) s[e] = 0.f;
    for (int i = lane; i < DM; i += 64) {
        float xv = xr[i];
#pragma unroll
        for (int e = 0; e < NE; e++) s[e] += xv * gw[e * DM + i];
    }
#pragma unroll
    for (int e = 0; e < NE; e++)
        for (int o = 32; o > 0; o >>= 1) s[e] += __shfl_down(s[e], o);
    if (lane == 0) {
        int i0 = 0; float l0 = s[0];
#pragma unroll
        for (int e = 1; e < NE; e++) if (s[e] > l0) { l0 = s[e]; i0 = e; }
        int i1 = -1; float l1 = -1e30f;
#pragma unroll
        for (int e = 0; e < NE; e++) if (e != i0 && s[e] > l1) { l1 = s[e]; i1 = e; }
        float e1 = __expf(l1 - l0);
        float inv = 1.f / (1.f + e1);
        topidx[t] = make_int2(i0, i1);
        topg[t]   = make_float2(inv, e1 * inv);
        atomicAdd(&cnt[i0], 1);
        atomicAdd(&cnt[i1], 1);
    }
}

__global__ void prefix_kernel(const int* __restrict__ cnt, int* __restrict__ offs) {
    if (threadIdx.x == 0) {
        int a = 0;
        for (int e = 0; e < NE; e++) { offs[e] = a; a += cnt[e]; }
    }
}

__global__ __launch_bounds__(256) void scatter_kernel(const int2* __restrict__ topidx,
                                                      const float2* __restrict__ topg,
                                                      const int* __restrict__ offs,
                                                      int* __restrict__ fill,
                                                      int* __restrict__ tok,
                                                      float* __restrict__ gate) {
    int t = blockIdx.x * 256 + threadIdx.x;
    if (t >= T_TOKENS) return;
    int2 ix = topidx[t]; float2 g = topg[t];
    int p = atomicAdd(&fill[ix.x], 1);
    int sl = offs[ix.x] + p;
    tok[sl] = t; gate[sl] = g.x;
    p = atomicAdd(&fill[ix.y], 1);
    sl = offs[ix.y] + p;
    tok[sl] = t; gate[sl] = g.y;
}

// ---- async-staged GEMM: C[M,N] = A[M,K] * B[N,K]^T, bf16, 128x128 tile -----
// Chunk swizzle: logical (row,kg) lives at physical chunk p = row*4 + (kg ^ ((row>>1)&3)).
// Staging inverse: p -> row=p>>2, kg=(p&3)^((row>>1)&3). Balances ds_read_b128
// bank-quads (each residue mod 8 hit exactly 2x per 16-lane group = free).
// MODE 0: shared L1 -> silu -> bf16   MODE 1: shared L2 -> f32 out
// MODE 2: expert L1 (gathered rows) -> silu -> bf16 at slots
// MODE 3: expert L2 -> gate-scaled atomicAdd into out
template<int MODE>
__global__ __launch_bounds__(256)
void gemm_async(const u16* __restrict__ A, int lda,
                const u16* __restrict__ Bbase, int ldb, long strideB, int K,
                int Mstatic,
                const int* __restrict__ cnt, const int* __restrict__ offs,
                const int* __restrict__ tok_of_slot, const float* __restrict__ gate_of_slot,
                u16* __restrict__ Cb, int ldcb,
                float* __restrict__ Cf, int ldcf) {
    int M = Mstatic, base = 0;
    const u16* B = Bbase;
    if constexpr (MODE >= 2) {
        int e = blockIdx.z;
        base = offs[e];
        M = cnt[e];
        B = Bbase + (long)e * strideB;
    }
    const int m0 = blockIdx.y * 128;
    if (m0 >= M) return;
    const int n0 = blockIdx.x * 128;

    __shared__ u16 As[128 * 32];   // unpadded: required by global_load_lds
    __shared__ u16 Bs[128 * 32];

    const int tid  = threadIdx.x;
    const int lane = tid & 63;
    const int wid  = tid >> 6;
    const int wm   = (wid >> 1) * 64;
    const int wn   = (wid & 1) * 64;
    const int lr   = lane & 15;

    // Staging: round i covers chunks p = i*256 + tid (16 B each).
    const u16* aptr[2]; const u16* bptr[2];
    u16* alds[2]; u16* blds[2];
#pragma unroll
    for (int i = 0; i < 2; i++) {
        int p = tid + i * 256;
        int r = p >> 2;
        int kg = (p & 3) ^ ((r >> 1) & 3);
        int rr = m0 + r;
        if (rr >= M) rr = M - 1;            // clamp tail (stores guarded)
        long grow;
        if constexpr (MODE == 2)      grow = tok_of_slot[base + rr];
        else if constexpr (MODE == 3) grow = (long)(base + rr);
        else                          grow = rr;
        aptr[i] = A + grow * (long)lda + kg * 8;
        bptr[i] = B + (long)(n0 + r) * ldb + kg * 8;
        alds[i] = As + (i * 256 + wid * 64) * 8;   // wave-uniform base
        blds[i] = Bs + (i * 256 + wid * 64) * 8;
    }

    // Fragment read offsets (elements). key invariant across mi/ni (steps of 16 rows).
    const int key  = (lr >> 1) & 3;
    const int kgx  = (lane >> 4) ^ key;
    const int aoe  = (wm + lr) * 32 + kgx * 8;
    const int boe  = (wn + lr) * 32 + kgx * 8;

    f32x4 acc[4][4];
#pragma unroll
    for (int mi = 0; mi < 4; mi++)
#pragma unroll
        for (int ni = 0; ni < 4; ni++)
            acc[mi][ni] = (f32x4){0.f, 0.f, 0.f, 0.f};

    for (int k0 = 0; k0 < K; k0 += 32) {
#pragma unroll
        for (int i = 0; i < 2; i++) {
            gld16(aptr[i] + k0, alds[i]);
            gld16(bptr[i] + k0, blds[i]);
        }
        __syncthreads();                    // compiler drains vmcnt before barrier
        short8 af[4], bfr[4];
#pragma unroll
        for (int mi = 0; mi < 4; mi++) af[mi]  = *(const short8*)&As[aoe + mi * 512];
#pragma unroll
        for (int ni = 0; ni < 4; ni++) bfr[ni] = *(const short8*)&Bs[boe + ni * 512];
#pragma unroll
        for (int mi = 0; mi < 4; mi++)
#pragma unroll
            for (int ni = 0; ni < 4; ni++)
                acc[mi][ni] = __builtin_amdgcn_mfma_f32_16x16x32_bf16(af[mi], bfr[ni],
                                                                      acc[mi][ni], 0, 0, 0);
        __syncthreads();
    }

    // Epilogue. C/D layout: col = lane&15, row = (lane>>4)*4 + reg  [m89-verified]
    const int r4 = (lane >> 4) * 4;
    const int cl = lane & 15;
#pragma unroll
    for (int mi = 0; mi < 4; mi++) {
#pragma unroll
        for (int rr = 0; rr < 4; rr++) {
            int row = m0 + wm + mi * 16 + r4 + rr;
            if constexpr (MODE >= 2) { if (row >= M) continue; }
            int t = 0; float g = 0.f;
            if constexpr (MODE == 3) {
                t = tok_of_slot[base + row];
                g = gate_of_slot[base + row];
            }
#pragma unroll
            for (int ni = 0; ni < 4; ni++) {
                int col = n0 + wn + ni * 16 + cl;
                float v = acc[mi][ni][rr];
                if constexpr (MODE == 0) {
                    float s = v / (1.f + __expf(-v));
                    Cb[(long)row * ldcb + col] = f2b(s);
                } else if constexpr (MODE == 1) {
                    Cf[(long)row * ldcf + col] = v;
                } else if constexpr (MODE == 2) {
                    float s = v / (1.f + __expf(-v));
                    Cb[(long)(base + row) * ldcb + col] = f2b(s);
                } else {
                    atomicAdd(&Cf[(long)t * ldcf + col], g * v);
                }
            }
        }
    }
}

// ---- fallback sync GEMM (fp32 B in-flight convert) for small-ws case -------
template<typename TB, int MODE>
__global__ __launch_bounds__(256)
void gemm_bt(const u16* __restrict__ A, int lda,
             const TB* __restrict__ Bbase, int ldb, long strideB, int K,
             int Mstatic,
             const int* __restrict__ cnt, const int* __restrict__ offs,
             const int* __restrict__ tok_of_slot, const float* __restrict__ gate_of_slot,
             u16* __restrict__ Cb, int ldcb,
             float* __restrict__ Cf, int ldcf) {
    int M = Mstatic, base = 0;
    const TB* B = Bbase;
    if constexpr (MODE >= 2) {
        int e = blockIdx.z;
        base = offs[e];
        M = cnt[e];
        B = Bbase + (long)e * strideB;
    }
    const int m0 = blockIdx.y * 128;
    if (m0 >= M) return;
    const int n0 = blockIdx.x * 128;

    __shared__ u16 As[128][40];
    __shared__ u16 Bs[128][40];

    const int tid  = threadIdx.x;
    const int lane = tid & 63;
    const int wid  = tid >> 6;
    const int wm   = (wid >> 1) * 64;
    const int wn   = (wid & 1) * 64;
    const int lr   = lane & 15;
    const int lk   = (lane >> 4) * 8;

    int arow_r[2], akc[2];
    long aoff[2], boff[2];
#pragma unroll
    for (int i = 0; i < 2; i++) {
        int c = tid + i * 256;
        int r = c >> 2, kc = (c & 3) * 8;
        arow_r[i] = r; akc[i] = kc;
        int rr = m0 + r;
        if (rr >= M) rr = M - 1;
        long grow;
        if constexpr (MODE == 2)      grow = tok_of_slot[base + rr];
        else if constexpr (MODE == 3) grow = (long)(base + rr);
        else                          grow = rr;
        aoff[i] = grow * (long)lda + kc;
        boff[i] = (long)(n0 + r) * ldb + kc;
    }

    f32x4 acc[4][4];
#pragma unroll
    for (int mi = 0; mi < 4; mi++)
#pragma unroll
        for (int ni = 0; ni < 4; ni++)
            acc[mi][ni] = (f32x4){0.f, 0.f, 0.f, 0.f};

    for (int k0 = 0; k0 < K; k0 += 32) {
#pragma unroll
        for (int i = 0; i < 2; i++) {
            *(uint4*)&As[arow_r[i]][akc[i]] = load8(A + aoff[i] + k0);
            *(uint4*)&Bs[arow_r[i]][akc[i]] = load8(B + boff[i] + k0);
        }
        __syncthreads();
        short8 af[4], bfr[4];
#pragma unroll
        for (int mi = 0; mi < 4; mi++) af[mi]  = *(const short8*)&As[wm + mi * 16 + lr][lk];
#pragma unroll
        for (int ni = 0; ni < 4; ni++) bfr[ni] = *(const short8*)&Bs[wn + ni * 16 + lr][lk];
#pragma unroll
        for (int mi = 0; mi < 4; mi++)
#pragma unroll
            for (int ni = 0; ni < 4; ni++)
                acc[mi][ni] = __builtin_amdgcn_mfma_f32_16x16x32_bf16(af[mi], bfr[ni],
                                                                      acc[mi][ni], 0, 0, 0);
        __syncthreads();
    }

    const int r4 = (lane >> 4) * 4;
    const int cl = lane & 15;
#pragma unroll
    for (int mi = 0; mi < 4; mi++) {
#pragma unroll
        for (int rr = 0; rr < 4; rr++) {
            int row = m0 + wm + mi * 16 + r4 + rr;
            if constexpr (MODE >= 2) { if (row >= M) continue; }
            int t = 0; float g = 0.f;
            if constexpr (MODE == 3) {
                t = tok_of_slot[base + row];
                g = gate_of_slot[base + row];
            }
#pragma unroll
            for (int ni = 0; ni < 4; ni++) {
                int col = n0 + wn + ni * 16 + cl;
                float v = acc[mi][ni][rr];
                if constexpr (MODE == 2) {
                    float s = v / (1.f + __expf(-v));
                    Cb[(long)(base + row) * ldcb + col] = f2b(s);
                } else if constexpr (MODE == 3) {
                    atomicAdd(&Cf[(long)t * ldcf + col], g * v);
                }
            }
        }
    }
}

extern "C" void kernel_launch(void* const* d_in, const int* in_sizes, int n_in,
                              void* d_out, int out_size, void* d_ws, size_t ws_size,
                              hipStream_t stream) {
    const float* x   = (const float*)d_in[0];
    const float* sw1 = (const float*)d_in[1];
    const float* sw2 = (const float*)d_in[2];
    const float* ew1 = (const float*)d_in[3];
    const float* ew2 = (const float*)d_in[4];
    const float* gw  = (const float*)d_in[5];
    float* out = (float*)d_out;

    char* ws = (char*)d_ws;
    size_t off = 0;
    auto alloc = [&](size_t bytes) -> char* {
        off = (off + 255) & ~(size_t)255;
        char* p = ws + off;
        off += bytes;
        return p;
    };

    int*    meta   = (int*)alloc(256);          // cnt[8] | fill[8] | offs[8]
    int*    cnt    = meta;
    int*    fill   = meta + 8;
    int*    offs   = meta + 16;
    int2*   topidx = (int2*)alloc((size_t)T_TOKENS * 8);
    float2* topg   = (float2*)alloc((size_t)T_TOKENS * 8);
    int*    tok    = (int*)alloc((size_t)2 * T_TOKENS * 4);
    float*  gate   = (float*)alloc((size_t)2 * T_TOKENS * 4);
    u16* xb   = (u16*)alloc((size_t)T_TOKENS * DM * 2);
    u16* sw1b = (u16*)alloc((size_t)HID * DM * 2);
    u16* sw2b = (u16*)alloc((size_t)DM * HID * 2);
    u16* hidS = (u16*)alloc((size_t)T_TOKENS * HID * 2);
    u16* hidE = (u16*)alloc((size_t)2 * T_TOKENS * HID * 2);

    const size_t ew_bytes = (size_t)NE * HID * DM * 2;   // 64 MB each
    bool cvt_ew = (ws_size >= off + 2 * ew_bytes + 1024);
    u16 *ew1b = nullptr, *ew2b = nullptr;
    if (cvt_ew) {
        ew1b = (u16*)alloc(ew_bytes);
        ew2b = (u16*)alloc(ew_bytes);
    }

    hipMemsetAsync(meta, 0, 64, stream);  // zero cnt+fill

    if (cvt_ew)
        cvt_all_kernel<true><<<(int)(CN4 / 2048), 256, 0, stream>>>(
            x, sw1, sw2, ew1, ew2, xb, sw1b, sw2b, ew1b, ew2b);
    else
        cvt_all_kernel<false><<<(int)(CN2 / 2048), 256, 0, stream>>>(
            x, sw1, sw2, nullptr, nullptr, xb, sw1b, sw2b, nullptr, nullptr);

    gate_kernel<<<T_TOKENS / 4, 256, 0, stream>>>(x, gw, cnt, topidx, topg);
    prefix_kernel<<<1, 64, 0, stream>>>(cnt, offs);
    scatter_kernel<<<T_TOKENS / 256, 256, 0, stream>>>(topidx, topg, offs, fill, tok, gate);

    dim3 blk(256);
    // shared L1: [T,1024] x [4096,1024]^T -> silu -> hidS (bf16)
    gemm_async<0><<<dim3(HID / 128, T_TOKENS / 128), blk, 0, stream>>>(
        xb, DM, sw1b, DM, 0, DM, T_TOKENS,
        nullptr, nullptr, nullptr, nullptr, hidS, HID, nullptr, 0);
    // expert L1: gathered rows, per-expert weights
    if (cvt_ew)
        gemm_async<2><<<dim3(HID / 128, T_TOKENS / 128, NE), blk, 0, stream>>>(
            xb, DM, ew1b, DM, (long)HID * DM, DM, 0,
            cnt, offs, tok, gate, hidE, HID, nullptr, 0);
    else
        gemm_bt<float, 2><<<dim3(HID / 128, T_TOKENS / 128, NE), blk, 0, stream>>>(
            xb, DM, ew1, DM, (long)HID * DM, DM, 0,
            cnt, offs, tok, gate, hidE, HID, nullptr, 0);
    // shared L2: [T,4096] x [1024,4096]^T -> out (f32 store, full coverage)
    gemm_async<1><<<dim3(DM / 128, T_TOKENS / 128), blk, 0, stream>>>(
        hidS, HID, sw2b, HID, 0, HID, T_TOKENS,
        nullptr, nullptr, nullptr, nullptr, nullptr, 0, out, DM);
    // expert L2: gate-scaled atomic add into out (stream-ordered after shared L2)
    if (cvt_ew)
        gemm_async<3><<<dim3(DM / 128, T_TOKENS / 128, NE), blk, 0, stream>>>(
            hidE, HID, ew2b, HID, (long)DM * HID, HID, 0,
            cnt, offs, tok, gate, nullptr, 0, out, DM);
    else
        gemm_bt<float, 3><<<dim3(DM / 128, T_TOKENS / 128, NE), blk, 0, stream>>>(
            hidE, HID, ew2, HID, (long)DM * HID, HID, 0,
            cnt, offs, tok, gate, nullptr, 0, out, DM);
}